// Round 1
// baseline (1289.815 us; speedup 1.0000x reference)
//
#include <hip/hip_runtime.h>

#define NE 8
#define NT 4096
#define NH 2048

typedef unsigned short u16_t;
typedef unsigned int u32_t;
typedef __attribute__((ext_vector_type(8))) short short8;    // 8 bf16 (4 VGPRs)
typedef __attribute__((ext_vector_type(4))) float floatx4;   // MFMA C/D

// f32 -> bf16, round-to-nearest-even (exact for ints |v|<=256, i.e. the weights)
static __device__ __forceinline__ u16_t f2bf(float f) {
  union { float fv; u32_t uv; } v; v.fv = f;
  u32_t r = v.uv + 0x7fffu + ((v.uv >> 16) & 1u);
  return (u16_t)(r >> 16);
}

// x[e][t][h] f32 -> xb bf16 (removes all conversion VALU from the GEMM hot loop)
__global__ __launch_bounds__(256)
void cvt_x_kernel(const float* __restrict__ x, u16_t* __restrict__ xb) {
  const size_t i = ((size_t)blockIdx.x * 256 + threadIdx.x) * 8;
  const float4 v0 = *(const float4*)(x + i);
  const float4 v1 = *(const float4*)(x + i + 4);
  uint4 o;
  o.x = (u32_t)f2bf(v0.x) | ((u32_t)f2bf(v0.y) << 16);
  o.y = (u32_t)f2bf(v0.z) | ((u32_t)f2bf(v0.w) << 16);
  o.z = (u32_t)f2bf(v1.x) | ((u32_t)f2bf(v1.y) << 16);
  o.w = (u32_t)f2bf(v1.z) | ((u32_t)f2bf(v1.w) << 16);
  *(uint4*)(xb + i) = o;
}

// w[e][k][n] int32 -> wt8[e][k/8][n][8] bf16  (k-chunk-blocked "transpose")
__global__ __launch_bounds__(256)
void cvt_w_kernel(const int* __restrict__ w, u16_t* __restrict__ wt) {
  size_t g = (size_t)blockIdx.x * 256 + threadIdx.x;
  const int n  = (int)(g & (NH - 1));
  const int k8 = (int)((g >> 11) & (NH / 8 - 1));
  const int e  = (int)(g >> 19);
  const int* src = w + ((size_t)e * NH + (size_t)k8 * 8) * NH + n;
  u32_t p[4];
#pragma unroll
  for (int j = 0; j < 4; ++j) {
    u32_t lo = (u32_t)f2bf((float)src[(size_t)(2 * j) * NH]);
    u32_t hi = (u32_t)f2bf((float)src[(size_t)(2 * j + 1) * NH]);
    p[j] = lo | (hi << 16);
  }
  uint4 v; v.x = p[0]; v.y = p[1]; v.z = p[2]; v.w = p[3];
  *(uint4*)(wt + (((size_t)e * (NH / 8) + k8) * NH + n) * 8) = v;
}

#define GLD(SRC, DST) \
  __builtin_amdgcn_global_load_lds((const __attribute__((address_space(1))) void*)(SRC), \
                                   (__attribute__((address_space(3))) void*)(DST), 16, 0, 0)

// Stage A half HH (rows HH*128..+128) of K-tile TT into buffer DD.
// LDS dest is linear; the GLOBAL source is pre-swizzled (chunk ^= row&7) so
// swizzled ds_reads see the right data (swizzle must be both-sides-or-neither).
#define STAGEA(DD, TT, HH) do {                                                   \
  _Pragma("unroll") for (int c_ = 0; c_ < 2; ++c_) {                              \
    const int rowL_ = c_ * 64 + wv * 8 + (ln >> 3);                               \
    const int chk_  = (ln & 7) ^ (ln >> 3);                                       \
    const u16_t* s_ = Ae + (size_t)(m0 + (HH) * 128 + rowL_) * 2048 + (TT) * 64 + chk_ * 8; \
    u16_t* d_ = &As[DD][((HH) * 128 + c_ * 64 + wv * 8) * 64];                    \
    GLD(s_, d_);                                                                  \
  }                                                                               \
} while (0)

// Stage B half HH (k8-local HH*4..+4) of K-tile TT into buffer DD. Blocked
// [k8][n][8] layout is naturally at the ds_read_b128 bank floor (no swizzle).
#define STAGEB(DD, TT, HH) do {                                                   \
  _Pragma("unroll") for (int c_ = 0; c_ < 2; ++c_) {                              \
    const int idx_ = c_ * 8 + wv;                                                 \
    const int k8l_ = (HH) * 4 + (idx_ >> 2);                                      \
    const int nq_  = (idx_ & 3) * 64;                                             \
    const u16_t* s_ = Be + ((size_t)((TT) * 8 + k8l_) * 2048 + n0 + nq_ + ln) * 8; \
    u16_t* d_ = &Bs[DD][(k8l_ * 256 + nq_) * 8];                                  \
    GLD(s_, d_);                                                                  \
  }                                                                               \
} while (0)

#define READA(DST, MS) do {                                                       \
  _Pragma("unroll") for (int fi = 0; fi < 4; ++fi) {                              \
    const int row_ = wm * 128 + (MS) * 64 + fi * 16 + l16;                        \
    _Pragma("unroll") for (int s = 0; s < 2; ++s) {                               \
      const int chk_ = (4 * s + q) ^ (row_ & 7);                                  \
      DST[fi][s] = *(const short8*)&As[cur][row_ * 64 + chk_ * 8];                \
    }                                                                             \
  }                                                                               \
} while (0)

#define READB(NS) do {                                                            \
  _Pragma("unroll") for (int j = 0; j < 2; ++j) {                                 \
    const int n_ = wn * 64 + (NS) * 32 + j * 16 + l16;                            \
    _Pragma("unroll") for (int s = 0; s < 2; ++s) {                               \
      bfr[j][s] = *(const short8*)&Bs[cur][((4 * s + q) * 256 + n_) * 8];         \
    }                                                                             \
  }                                                                               \
} while (0)

// 16 MFMAs = one C-quadrant x K=64 (all indices compile-time constant)
#define MMQ(AF, MI0, NJ0)                                                         \
  _Pragma("unroll") for (int fi = 0; fi < 4; ++fi)                                \
  _Pragma("unroll") for (int j = 0; j < 2; ++j)                                   \
  _Pragma("unroll") for (int s = 0; s < 2; ++s)                                   \
    acc[(MI0) + fi][(NJ0) + j] = __builtin_amdgcn_mfma_f32_16x16x32_bf16(         \
        AF[fi][s], bfr[j][s], acc[(MI0) + fi][(NJ0) + j], 0, 0, 0);

#define BAR()  __builtin_amdgcn_s_barrier()
#define PRIO(P) __builtin_amdgcn_s_setprio(P)

// C[e][m][n] = (A[e][m][k] @ B[e][k][n]) * scale[e][n]
// 256x256 tile, BK=64, 8 waves (2Mx4N), double-buffered 128KiB LDS,
// 8-phase schedule with counted vmcnt (T2+T3+T4+T5).
template <typename OT>
__global__ __launch_bounds__(512, 2)
void gemm8p_kernel(const u16_t* __restrict__ A, const u16_t* __restrict__ BT8,
                   const float* __restrict__ scale, OT* __restrict__ C) {
  constexpr int M = NT, N = NH, K = NH;
  constexpr int NKT = K / 64;                 // 32 K-tiles
  const int e  = blockIdx.z;
  const int n0 = blockIdx.x * 256;
  const int m0 = blockIdx.y * 256;
  const int tid = (int)threadIdx.x;
  const int wv = tid >> 6, ln = tid & 63;
  const int wm = wv >> 2, wn = wv & 3;        // 2M x 4N wave grid
  const int q = ln >> 4, l16 = ln & 15;

  const u16_t* Ae = A + (size_t)e * M * K;
  const u16_t* Be = BT8 + (size_t)e * K * N;  // [k8][n][8] blocked
  const float* se = scale + (size_t)e * N;
  OT* Ce = C + (size_t)e * (size_t)M * N;

  // A: [256 rows][64 k] bf16 per buffer (32 KB); B: [8 k8][256 n][8] (32 KB)
  __shared__ __align__(16) u16_t As[2][256 * 64];
  __shared__ __align__(16) u16_t Bs[2][8 * 256 * 8];

  floatx4 acc[8][4] = {};
  short8 a0[4][2], a1[4][2];   // A m-sub fragments, cached across phases
  short8 bfr[2][2];            // B n-sub fragments (n0 then n1, reg-reused)

  // Prologue: A(0), B(0), A(1) in flight (12 loads); B(1) issues in block 0.
  STAGEA(0, 0, 0); STAGEA(0, 0, 1);
  STAGEB(0, 0, 0); STAGEB(0, 0, 1);
  STAGEA(1, 1, 0); STAGEA(1, 1, 1);

  for (int u = 0; u < NKT; ++u) {
    const int cur = u & 1;
    // Block fence: A(u),B(u) landed; A(u+1) (4 insts) stays in flight — never
    // drain to 0 in steady state (T4). Tail drains fully.
    if (u + 1 < NKT) { asm volatile("s_waitcnt vmcnt(4)" ::: "memory"); }
    else             { asm volatile("s_waitcnt vmcnt(0)" ::: "memory"); }
    BAR();

    // ---- phase 0: read A-m0 (8) + B-n0 (4); stage B(u+1)h0; MFMA q(0,0)
    READA(a0, 0);
    READB(0);
    if (u + 1 < NKT) STAGEB(cur ^ 1, u + 1, 0);
    BAR(); PRIO(1);
    MMQ(a0, 0, 0);
    PRIO(0); BAR();

    // ---- phase 1: read A-m1 (8); stage B(u+1)h1; MFMA q(1,0)
    READA(a1, 1);
    if (u + 1 < NKT) STAGEB(cur ^ 1, u + 1, 1);
    BAR(); PRIO(1);
    MMQ(a1, 4, 0);
    PRIO(0); BAR();

    // ---- phase 2: read B-n1 (4); stage A(u+2)h0 (A reads of cur done at
    //      phase-1 barrier since a0/a1 are register-cached); MFMA q(0,1)
    READB(1);
    if (u + 2 < NKT) STAGEA(cur, u + 2, 0);
    BAR(); PRIO(1);
    MMQ(a0, 0, 2);
    PRIO(0); BAR();

    // ---- phase 3: stage A(u+2)h1; MFMA q(1,1)
    if (u + 2 < NKT) STAGEA(cur, u + 2, 1);
    BAR(); PRIO(1);
    MMQ(a1, 4, 2);
    PRIO(0); BAR();
  }

  // Epilogue: scale per output column, write C.
  float scl[4];
#pragma unroll
  for (int ni = 0; ni < 4; ++ni) scl[ni] = se[n0 + wn * 64 + ni * 16 + l16];
#pragma unroll
  for (int mi = 0; mi < 8; ++mi) {
    const int row = m0 + wm * 128 + (mi >> 2) * 64 + (mi & 3) * 16 + q * 4;
#pragma unroll
    for (int r = 0; r < 4; ++r) {
#pragma unroll
      for (int ni = 0; ni < 4; ++ni) {
        const float v = acc[mi][ni][r] * scl[ni];
        const int col = n0 + wn * 64 + ni * 16 + l16;
        if constexpr (sizeof(OT) == 2) {
          Ce[(size_t)(row + r) * N + col] = f2bf(v);   // h as bf16
        } else {
          Ce[(size_t)(row + r) * N + col] = v;         // final out f32
        }
      }
    }
  }
}

extern "C" void kernel_launch(void* const* d_in, const int* in_sizes, int n_in,
                              void* d_out, int out_size, void* d_ws, size_t ws_size,
                              hipStream_t stream) {
  const float* x   = (const float*)d_in[0];
  const int*   w1q = (const int*)d_in[1];
  const float* s1  = (const float*)d_in[2];
  const int*   w2q = (const int*)d_in[3];
  const float* s2  = (const float*)d_in[4];
  float* out = (float*)d_out;

  // ws layout: h (E*T*H bf16 = 128 MiB) | wt (E*H*H bf16 = 64 MiB, reused).
  // xb (bf16 x, 128 MiB) lives in d_out, which is dead until GEMM2 writes it.
  u16_t* h  = (u16_t*)d_ws;
  u16_t* wt = (u16_t*)d_ws + (size_t)NE * NT * NH;
  u16_t* xb = (u16_t*)d_out;

  const int cvtx_blocks = (int)(((size_t)NE * NT * NH) / 2048);   // 32768
  const int cvtw_blocks = (NE * (NH / 8) * NH) / 256;             // 16384
  dim3 ggrid(NH / 256, NT / 256, NE);                             // 8 x 16 x 8

  cvt_x_kernel<<<cvtx_blocks, 256, 0, stream>>>(x, xb);
  cvt_w_kernel<<<cvtw_blocks, 256, 0, stream>>>(w1q, wt);
  gemm8p_kernel<u16_t><<<ggrid, 512, 0, stream>>>(xb, wt, s1, h);
  cvt_w_kernel<<<cvtw_blocks, 256, 0, stream>>>(w2q, wt);
  gemm8p_kernel<float><<<ggrid, 512, 0, stream>>>(h, wt, s2, out);
}

// Round 2
// 1084.465 us; speedup vs baseline: 1.1894x; 1.1894x over previous
//
#include <hip/hip_runtime.h>

#define NE 8
#define NT 4096
#define NH 2048

typedef unsigned short u16_t;
typedef unsigned int u32_t;
typedef __attribute__((ext_vector_type(8))) short short8;    // 8 bf16 (4 VGPRs)
typedef __attribute__((ext_vector_type(4))) float floatx4;   // MFMA C/D

// f32 -> bf16, round-to-nearest-even (exact for ints |v|<=256, i.e. the weights)
static __device__ __forceinline__ u16_t f2bf(float f) {
  union { float fv; u32_t uv; } v; v.fv = f;
  u32_t r = v.uv + 0x7fffu + ((v.uv >> 16) & 1u);
  return (u16_t)(r >> 16);
}

// x[e][t][h] f32 -> xb bf16 (removes all conversion VALU from the GEMM hot loop)
__global__ __launch_bounds__(256)
void cvt_x_kernel(const float* __restrict__ x, u16_t* __restrict__ xb) {
  const size_t i = ((size_t)blockIdx.x * 256 + threadIdx.x) * 8;
  const float4 v0 = *(const float4*)(x + i);
  const float4 v1 = *(const float4*)(x + i + 4);
  uint4 o;
  o.x = (u32_t)f2bf(v0.x) | ((u32_t)f2bf(v0.y) << 16);
  o.y = (u32_t)f2bf(v0.z) | ((u32_t)f2bf(v0.w) << 16);
  o.z = (u32_t)f2bf(v1.x) | ((u32_t)f2bf(v1.y) << 16);
  o.w = (u32_t)f2bf(v1.z) | ((u32_t)f2bf(v1.w) << 16);
  *(uint4*)(xb + i) = o;
}

// w[e][k][n] int32 -> wt8[e][k/8][n][8] bf16  (k-chunk-blocked "transpose")
__global__ __launch_bounds__(256)
void cvt_w_kernel(const int* __restrict__ w, u16_t* __restrict__ wt) {
  size_t g = (size_t)blockIdx.x * 256 + threadIdx.x;
  const int n  = (int)(g & (NH - 1));
  const int k8 = (int)((g >> 11) & (NH / 8 - 1));
  const int e  = (int)(g >> 19);
  const int* src = w + ((size_t)e * NH + (size_t)k8 * 8) * NH + n;
  u32_t p[4];
#pragma unroll
  for (int j = 0; j < 4; ++j) {
    u32_t lo = (u32_t)f2bf((float)src[(size_t)(2 * j) * NH]);
    u32_t hi = (u32_t)f2bf((float)src[(size_t)(2 * j + 1) * NH]);
    p[j] = lo | (hi << 16);
  }
  uint4 v; v.x = p[0]; v.y = p[1]; v.z = p[2]; v.w = p[3];
  *(uint4*)(wt + (((size_t)e * (NH / 8) + k8) * NH + n) * 8) = v;
}

#define GLD(SRC, DST) \
  __builtin_amdgcn_global_load_lds((const __attribute__((address_space(1))) void*)(SRC), \
                                   (__attribute__((address_space(3))) void*)(DST), 16, 0, 0)

// Inline-asm LDS read: invisible to alias analysis so the compiler cannot
// see a (global_load_lds -> ds_read) dependency and insert vmcnt(0) drains
// that defeat the counted-vmcnt pipeline (rule #18 / m201 template).
static __device__ __forceinline__ short8 dsr128(const u16_t* p) {
  short8 r;
  const u32_t a = (u32_t)(size_t)(const __attribute__((address_space(3))) u16_t*)p;
  asm volatile("ds_read_b128 %0, %1" : "=v"(r) : "v"(a));
  return r;
}

// Stage A half HH (rows HH*128..+128) of K-tile TT into buffer DD.
// LDS dest is linear; the GLOBAL source is pre-swizzled (chunk ^= row&7) so
// swizzled ds_reads see the right data (swizzle must be both-sides-or-neither).
#define STAGEA(DD, TT, HH) do {                                                   \
  _Pragma("unroll") for (int c_ = 0; c_ < 2; ++c_) {                              \
    const int rowL_ = c_ * 64 + wv * 8 + (ln >> 3);                               \
    const int chk_  = (ln & 7) ^ (ln >> 3);                                       \
    const u16_t* s_ = Ae + (size_t)(m0 + (HH) * 128 + rowL_) * 2048 + (TT) * 64 + chk_ * 8; \
    u16_t* d_ = &As[DD][((HH) * 128 + c_ * 64 + wv * 8) * 64];                    \
    GLD(s_, d_);                                                                  \
  }                                                                               \
} while (0)

// Stage B half HH (k8-local HH*4..+4) of K-tile TT into buffer DD. Blocked
// [k8][n][8] layout is naturally at the ds_read_b128 bank floor (no swizzle).
#define STAGEB(DD, TT, HH) do {                                                   \
  _Pragma("unroll") for (int c_ = 0; c_ < 2; ++c_) {                              \
    const int idx_ = c_ * 8 + wv;                                                 \
    const int k8l_ = (HH) * 4 + (idx_ >> 2);                                      \
    const int nq_  = (idx_ & 3) * 64;                                             \
    const u16_t* s_ = Be + ((size_t)((TT) * 8 + k8l_) * 2048 + n0 + nq_ + ln) * 8; \
    u16_t* d_ = &Bs[DD][(k8l_ * 256 + nq_) * 8];                                  \
    GLD(s_, d_);                                                                  \
  }                                                                               \
} while (0)

#define READA(DST, MS) do {                                                       \
  _Pragma("unroll") for (int fi = 0; fi < 4; ++fi) {                              \
    const int row_ = wm * 128 + (MS) * 64 + fi * 16 + l16;                        \
    _Pragma("unroll") for (int s = 0; s < 2; ++s) {                               \
      const int chk_ = (4 * s + q) ^ (row_ & 7);                                  \
      DST[fi][s] = dsr128(&As[cur][row_ * 64 + chk_ * 8]);                        \
    }                                                                             \
  }                                                                               \
} while (0)

#define READB(NS) do {                                                            \
  _Pragma("unroll") for (int j = 0; j < 2; ++j) {                                 \
    const int n_ = wn * 64 + (NS) * 32 + j * 16 + l16;                            \
    _Pragma("unroll") for (int s = 0; s < 2; ++s) {                               \
      bfr[j][s] = dsr128(&Bs[cur][((4 * s + q) * 256 + n_) * 8]);                 \
    }                                                                             \
  }                                                                               \
} while (0)

// 16 MFMAs = one C-quadrant x K=64 (all indices compile-time constant)
#define MMQ(AF, MI0, NJ0)                                                         \
  _Pragma("unroll") for (int fi = 0; fi < 4; ++fi)                                \
  _Pragma("unroll") for (int j = 0; j < 2; ++j)                                   \
  _Pragma("unroll") for (int s = 0; s < 2; ++s)                                   \
    acc[(MI0) + fi][(NJ0) + j] = __builtin_amdgcn_mfma_f32_16x16x32_bf16(         \
        AF[fi][s], bfr[j][s], acc[(MI0) + fi][(NJ0) + j], 0, 0, 0);

#define BAR()  __builtin_amdgcn_s_barrier()
#define PRIO(P) __builtin_amdgcn_s_setprio(P)
// All LDS reads issued this phase are done; fence the scheduler so MFMAs
// cannot be hoisted above the wait (rule #18).
#define LDSWAIT() do {                                          \
  asm volatile("s_waitcnt lgkmcnt(0)" ::: "memory");            \
  __builtin_amdgcn_sched_barrier(0);                            \
} while (0)

// C[e][m][n] = (A[e][m][k] @ B[e][k][n]) * scale[e][n]
// 256x256 tile, BK=64, 8 waves (2Mx4N), double-buffered 128KiB LDS,
// 8-phase schedule with counted vmcnt (T2+T3+T4+T5), asm ds_reads.
template <typename OT>
__global__ __launch_bounds__(512, 2)
void gemm8p_kernel(const u16_t* __restrict__ A, const u16_t* __restrict__ BT8,
                   const float* __restrict__ scale, OT* __restrict__ C) {
  constexpr int M = NT, N = NH, K = NH;
  constexpr int NKT = K / 64;                 // 32 K-tiles
  const int e  = blockIdx.z;
  const int n0 = blockIdx.x * 256;
  const int m0 = blockIdx.y * 256;
  const int tid = (int)threadIdx.x;
  const int wv = tid >> 6, ln = tid & 63;
  const int wm = wv >> 2, wn = wv & 3;        // 2M x 4N wave grid
  const int q = ln >> 4, l16 = ln & 15;

  const u16_t* Ae = A + (size_t)e * M * K;
  const u16_t* Be = BT8 + (size_t)e * K * N;  // [k8][n][8] blocked
  const float* se = scale + (size_t)e * N;
  OT* Ce = C + (size_t)e * (size_t)M * N;

  // A: [256 rows][64 k] bf16 per buffer (32 KB); B: [8 k8][256 n][8] (32 KB)
  __shared__ __align__(16) u16_t As[2][256 * 64];
  __shared__ __align__(16) u16_t Bs[2][8 * 256 * 8];

  floatx4 acc[8][4] = {};
  short8 a0[4][2], a1[4][2];   // A m-sub fragments, cached across phases
  short8 bfr[2][2];            // B n-sub fragments (n0 then n1, reg-reused)

  // Prologue: A(0), B(0), A(1) in flight (12 loads); B(1) issues in block 0.
  STAGEA(0, 0, 0); STAGEA(0, 0, 1);
  STAGEB(0, 0, 0); STAGEB(0, 0, 1);
  STAGEA(1, 1, 0); STAGEA(1, 1, 1);

  for (int u = 0; u < NKT; ++u) {
    const int cur = u & 1;
    // Block fence: A(u),B(u) landed; A(u+1) (4 insts) stays in flight — never
    // drain to 0 in steady state (T4). Tail drains fully.
    if (u + 1 < NKT) { asm volatile("s_waitcnt vmcnt(4)" ::: "memory"); }
    else             { asm volatile("s_waitcnt vmcnt(0)" ::: "memory"); }
    BAR();

    // ---- phase 0: read A-m0 (8) + B-n0 (4); stage B(u+1)h0; MFMA q(0,0)
    READA(a0, 0);
    READB(0);
    if (u + 1 < NKT) STAGEB(cur ^ 1, u + 1, 0);
    BAR(); LDSWAIT(); PRIO(1);
    MMQ(a0, 0, 0);
    PRIO(0); BAR();

    // ---- phase 1: read A-m1 (8); stage B(u+1)h1; MFMA q(1,0)
    READA(a1, 1);
    if (u + 1 < NKT) STAGEB(cur ^ 1, u + 1, 1);
    BAR(); LDSWAIT(); PRIO(1);
    MMQ(a1, 4, 0);
    PRIO(0); BAR();

    // ---- phase 2: read B-n1 (4); stage A(u+2)h0 (A reads of cur done at
    //      phase-1 barrier since a0/a1 are register-cached); MFMA q(0,1)
    READB(1);
    if (u + 2 < NKT) STAGEA(cur, u + 2, 0);
    BAR(); LDSWAIT(); PRIO(1);
    MMQ(a0, 0, 2);
    PRIO(0); BAR();

    // ---- phase 3: stage A(u+2)h1; MFMA q(1,1)
    if (u + 2 < NKT) STAGEA(cur, u + 2, 1);
    BAR(); LDSWAIT(); PRIO(1);
    MMQ(a1, 4, 2);
    PRIO(0); BAR();
  }

  // Epilogue: scale per output column, write C.
  float scl[4];
#pragma unroll
  for (int ni = 0; ni < 4; ++ni) scl[ni] = se[n0 + wn * 64 + ni * 16 + l16];
#pragma unroll
  for (int mi = 0; mi < 8; ++mi) {
    const int row = m0 + wm * 128 + (mi >> 2) * 64 + (mi & 3) * 16 + q * 4;
#pragma unroll
    for (int r = 0; r < 4; ++r) {
#pragma unroll
      for (int ni = 0; ni < 4; ++ni) {
        const float v = acc[mi][ni][r] * scl[ni];
        const int col = n0 + wn * 64 + ni * 16 + l16;
        if constexpr (sizeof(OT) == 2) {
          Ce[(size_t)(row + r) * N + col] = f2bf(v);   // h as bf16
        } else {
          Ce[(size_t)(row + r) * N + col] = v;         // final out f32
        }
      }
    }
  }
}

extern "C" void kernel_launch(void* const* d_in, const int* in_sizes, int n_in,
                              void* d_out, int out_size, void* d_ws, size_t ws_size,
                              hipStream_t stream) {
  const float* x   = (const float*)d_in[0];
  const int*   w1q = (const int*)d_in[1];
  const float* s1  = (const float*)d_in[2];
  const int*   w2q = (const int*)d_in[3];
  const float* s2  = (const float*)d_in[4];
  float* out = (float*)d_out;

  // ws layout: h (E*T*H bf16 = 128 MiB) | wt (E*H*H bf16 = 64 MiB, reused).
  // xb (bf16 x, 128 MiB) lives in d_out, which is dead until GEMM2 writes it.
  u16_t* h  = (u16_t*)d_ws;
  u16_t* wt = (u16_t*)d_ws + (size_t)NE * NT * NH;
  u16_t* xb = (u16_t*)d_out;

  const int cvtx_blocks = (int)(((size_t)NE * NT * NH) / 2048);   // 32768
  const int cvtw_blocks = (NE * (NH / 8) * NH) / 256;             // 16384
  dim3 ggrid(NH / 256, NT / 256, NE);                             // 8 x 16 x 8

  cvt_x_kernel<<<cvtx_blocks, 256, 0, stream>>>(x, xb);
  cvt_w_kernel<<<cvtw_blocks, 256, 0, stream>>>(w1q, wt);
  gemm8p_kernel<u16_t><<<ggrid, 512, 0, stream>>>(xb, wt, s1, h);
  cvt_w_kernel<<<cvtw_blocks, 256, 0, stream>>>(w2q, wt);
  gemm8p_kernel<float><<<ggrid, 512, 0, stream>>>(h, wt, s2, out);
}